// Round 6
// baseline (137.982 us; speedup 1.0000x reference)
//
#include <hip/hip_runtime.h>

// 14-step recurrence, single persistent kernel — DATA-IS-THE-FLAG protocol.
//   temp = J @ r_{t-1}; U = temp + Iext; sq = (0.2U)^2; s = 0.005*sum(sq); r_t = sq/s
// Carry UNNORMALIZED r̃_t = sq_t:  J@r_{t-1} = (J@r̃_{t-1})/s_{t-1}.
//
// R6 vs R5: the barrier is GONE. sq >= 0 always; the 0xAA ws poison is a
// NEGATIVE float. 14 write-once r̃ buffers; a reader polls its own operand
// loads (dev-scope u64 pairs, L2-bypass -> always L3-fresh) until every
// component's sign bit is clear. The successful poll's values ARE the data —
// no flag/data ordering hazard exists by construction. Since every wave reads
// the full vector anyway, s_{t-1} = 0.005 * wave_reduce(sum of components):
// no partials, no packs, no fences, no syncthreads, no waitcnt drains.
// Publisher: lanes 0..2 each fire-and-forget one dev-scope dword store.

#define N 1680
#define NV4 420            // N/4
#define NBLK 140
#define BLOCK 256
#define WAVES 4
#define RPW 3              // 140*4*3 = 1680 rows
#define NSTEP 14

typedef unsigned long long u64;
typedef unsigned int u32;

#define SIGNS 0x8000000080000000ULL

__device__ __forceinline__ float wave_reduce(float v) {
    #pragma unroll
    for (int off = 32; off; off >>= 1) v += __shfl_xor(v, off, 64);
    return v;
}
__device__ __forceinline__ void stf_dev(float* p, float v) {
    __hip_atomic_store(p, v, __ATOMIC_RELAXED, __HIP_MEMORY_SCOPE_AGENT);
}
__device__ __forceinline__ u64 ld8_dev(const u64* p) {
    return __hip_atomic_load(p, __ATOMIC_RELAXED, __HIP_MEMORY_SCOPE_AGENT);
}

__global__ __launch_bounds__(BLOCK, 1) void cann_persistent(
    const float* __restrict__ J,
    const float* __restrict__ net_in,      // [0,N): Iext, [N,2N): r0
    float* __restrict__ d_out,             // U(1680) | recSum(1) | r(1680)
    float* __restrict__ rbufs)             // NSTEP * N floats, write-once each
{
    const int tid   = threadIdx.x;
    const int lane  = tid & 63;
    const int wave  = tid >> 6;
    const int gwave = blockIdx.x * WAVES + wave;   // 0..559
    const int row0  = gwave * RPW;

    float iext[RPW];
    #pragma unroll
    for (int r = 0; r < RPW; ++r) iext[r] = net_in[row0 + r];

    // prologue: J rows -> regs (cold: HBM)
    float4 Jreg[RPW][7];
    #pragma unroll
    for (int r = 0; r < RPW; ++r) {
        const float4* Jrow = (const float4*)(J + (size_t)(row0 + r) * N);
        #pragma unroll
        for (int k = 0; k < 7; ++k) {
            const int idx = lane + 64 * k;
            Jreg[r][k] = (idx < NV4) ? Jrow[idx] : make_float4(0.f, 0.f, 0.f, 0.f);
        }
    }

    float sq3[RPW];          // all lanes hold all 3 (acc is butterfly-broadcast)

    for (int t = 0; t < NSTEP; ++t) {
        // ---- operand fetch == barrier: poll until all sign bits clear ----
        float4 rv[7];
        float s_prev = 1.0f;
        if (t == 0) {
            const float4* rp = (const float4*)(net_in + N);    // r0, plain loads
            #pragma unroll
            for (int j = 0; j < 7; ++j) {
                const int idx = lane + 64 * j;
                rv[j] = (idx < NV4) ? rp[idx] : make_float4(0.f, 0.f, 0.f, 0.f);
            }
        } else {
            const u64* b2 = (const u64*)(rbufs + (size_t)(t - 1) * N);
            for (;;) {
                bool ok = true;
                #pragma unroll
                for (int j = 0; j < 7; ++j) {
                    const int idx = lane + 64 * j;
                    if (idx < NV4) {
                        const u64 a = ld8_dev(b2 + 2 * idx);
                        const u64 b = ld8_dev(b2 + 2 * idx + 1);
                        ok = ok && !((a | b) & SIGNS);         // poison < 0, sq >= 0
                        rv[j].x = __uint_as_float((u32)a);
                        rv[j].y = __uint_as_float((u32)(a >> 32));
                        rv[j].z = __uint_as_float((u32)b);
                        rv[j].w = __uint_as_float((u32)(b >> 32));
                    } else rv[j] = make_float4(0.f, 0.f, 0.f, 0.f);
                }
                if (__all(ok)) break;
                __builtin_amdgcn_s_sleep(1);
            }
            // whole vector is in hand -> s_{t-1} is free
            float sv = 0.f;
            #pragma unroll
            for (int j = 0; j < 7; ++j) sv += rv[j].x + rv[j].y + rv[j].z + rv[j].w;
            s_prev = 0.005f * wave_reduce(sv);
        }

        // ---- dot(J_row, r̃) from registers; butterfly-broadcast sums ----
        #pragma unroll
        for (int r = 0; r < RPW; ++r) {
            float a = 0.f;
            #pragma unroll
            for (int k = 0; k < 7; ++k) {
                const float4 j4 = Jreg[r][k], r4 = rv[k];
                a += j4.x * r4.x + j4.y * r4.y + j4.z * r4.z + j4.w * r4.w;
            }
            const float acc = wave_reduce(a);                  // all lanes
            const float U   = acc / s_prev + iext[r];          // ALPHA=BETA=1
            const float u2  = 0.2f * U;
            sq3[r] = u2 * u2;
            if (t == NSTEP - 1 && lane == 0) d_out[row0 + r] = U;   // U_13
        }

        // ---- publish: lanes 0..2 fire-and-forget one dword each ----
        {
            const float v = (lane == 0) ? sq3[0] : ((lane == 1) ? sq3[1] : sq3[2]);
            if (lane < RPW) stf_dev(&rbufs[(size_t)t * N + row0 + lane], v);
        }

        // ---- J refresh for next step: L2 hits, hidden under the next poll ----
        if (t < NSTEP - 1) {
            #pragma unroll
            for (int r = 0; r < RPW; ++r) {
                const float4* Jrow = (const float4*)(J + (size_t)(row0 + r) * N);
                #pragma unroll
                for (int k = 0; k < 7; ++k) {
                    const int idx = lane + 64 * k;
                    if (idx < NV4) Jreg[r][k] = Jrow[idx];
                }
            }
        }
    }

    // ---- epilogue: poll rbufs[13] for s_13 ----
    {
        const u64* b2 = (const u64*)(rbufs + (size_t)(NSTEP - 1) * N);
        float sv;
        for (;;) {
            bool ok = true;
            sv = 0.f;
            #pragma unroll
            for (int j = 0; j < 7; ++j) {
                const int idx = lane + 64 * j;
                if (idx < NV4) {
                    const u64 a = ld8_dev(b2 + 2 * idx);
                    const u64 b = ld8_dev(b2 + 2 * idx + 1);
                    ok = ok && !((a | b) & SIGNS);
                    sv += __uint_as_float((u32)a) + __uint_as_float((u32)(a >> 32))
                        + __uint_as_float((u32)b) + __uint_as_float((u32)(b >> 32));
                }
            }
            if (__all(ok)) break;
            __builtin_amdgcn_s_sleep(1);
        }
        const float s = 0.005f * wave_reduce(sv);              // recSum_13
        if (gwave == 0 && lane == 0) d_out[N] = s;
        if (lane < RPW) {
            const float q = (lane == 0) ? sq3[0] : ((lane == 1) ? sq3[1] : sq3[2]);
            d_out[N + 1 + row0 + lane] = q / s;                // r_13
        }
    }
}

extern "C" void kernel_launch(void* const* d_in, const int* in_sizes, int n_in,
                              void* d_out, int out_size, void* d_ws, size_t ws_size,
                              hipStream_t stream) {
    const float* net_in = (const float*)d_in[0];
    const float* J      = (const float*)d_in[1];
    float* out = (float*)d_out;
    float* rbufs = (float*)d_ws;    // 14*1680 floats = 94 KB, 0xAA-poisoned (<0)

    cann_persistent<<<NBLK, BLOCK, 0, stream>>>(J, net_in, out, rbufs);
}